// Round 10
// baseline (351.907 us; speedup 1.0000x reference)
//
#include <hip/hip_runtime.h>
#include <hip/hip_cooperative_groups.h>
#include <stdint.h>

namespace cg = cooperative_groups;

#define Bb 8
#define Ss 2048
#define Dd 512

typedef _Float16 half8 __attribute__((ext_vector_type(8)));
typedef float floatx4 __attribute__((ext_vector_type(4)));

// ---------------- merged prep: x f32->f16 copy + 3x weight transpose, ONE dispatch ----------------
__global__ void prep_kernel(const float* __restrict__ x, _Float16* __restrict__ xb,
                            const float* __restrict__ Wq, const float* __restrict__ Wk,
                            const float* __restrict__ Wv, _Float16* __restrict__ wt) {
    const int bid = blockIdx.x;
    const int tid = threadIdx.x;
    if (bid < 4096) {
        int i = (bid * 256 + tid) * 8;
        float4 a = *(const float4*)(x + i);
        float4 b = *(const float4*)(x + i + 4);
        half8 h;
        h[0] = (_Float16)a.x; h[1] = (_Float16)a.y; h[2] = (_Float16)a.z; h[3] = (_Float16)a.w;
        h[4] = (_Float16)b.x; h[5] = (_Float16)b.y; h[6] = (_Float16)b.z; h[7] = (_Float16)b.w;
        *(half8*)(xb + i) = h;
    } else {
        __shared__ float t[32][33];
        const int b2 = bid - 4096;           // 0..767
        const int mz = b2 >> 8;              // matrix 0..2
        const int t2 = b2 & 255;             // tile 0..255
        const float* W = (mz == 0) ? Wq : ((mz == 1) ? Wk : Wv);
        _Float16* Wt = wt + (size_t)mz * Dd * Dd;
        const int c0 = (t2 & 15) * 32, r0 = (t2 >> 4) * 32;
        const int lx = tid & 31, ly = tid >> 5;  // ly 0..7
#pragma unroll
        for (int i = 0; i < 32; i += 8)
            t[ly + i][lx] = W[(size_t)(r0 + ly + i) * Dd + c0 + lx];
        __syncthreads();
#pragma unroll
        for (int i = 0; i < 32; i += 8)
            Wt[(size_t)(c0 + ly + i) * Dd + r0 + lx] = (_Float16)t[lx][ly + i];
    }
}

__device__ __forceinline__ void gl_lds16(const _Float16* g, _Float16* l) {
    __builtin_amdgcn_global_load_lds(
        (__attribute__((address_space(1))) void*)(g),
        (__attribute__((address_space(3))) void*)(l), 16, 0, 0);
}

// ---------------- fused proj + attn: ONE cooperative dispatch ----------------
// r9 ledger: rest = 119-130us across 5 proj structures vs 15-40us pipe models,
// and proj can never surface in top-5 under ~15 attn replays at 126us. This
// kernel makes proj measurable (fused dispatch tops the list; proj-phase =
// fused_dur - 126us) AND deletes all proj->attn inter-dispatch effects.
// Phase A (proj): 2 engines x 3 rounds x 256 blocks = 1536 tiles, exact r9 tile
//   body per engine (tid&255); engines touch disjoint 34.8KB LDS halves; barrier
//   counts identical across engines so __syncthreads stays block-uniform.
//   Block's 6 tiles = one A-panel x 6 n-panels -> A-panel L2-resident on its XCD.
// grid.sync (cooperative; all 256 blocks co-resident at 1 block/CU, 142.8KB LDS)
//   + __threadfence for cross-XCD visibility of q/k/vt.
// Phase B (attn): frozen r0 body, b=bid>>5, qt=bid&31 (same mapping as 2D grid).
#define KSTR 520   // K row stride (halves)
#define PSTR 40    // P row stride (halves)

__launch_bounds__(512, 2)
__global__ void fused_kernel(const _Float16* __restrict__ xb,
                             const _Float16* __restrict__ wt,   // [1536][512] concat B^T
                             const float* __restrict__ bq,
                             const float* __restrict__ bk,
                             const float* __restrict__ bv,
                             _Float16* __restrict__ qo,
                             _Float16* __restrict__ ko,
                             _Float16* __restrict__ vto,
                             float* __restrict__ out) {
    __shared__ __align__(16) unsigned char smem[142848];
    const int bid = blockIdx.x;
    const int tid = threadIdx.x;

    // ================= phase A: QKV projection =================
    {
        const int eng = tid >> 8;            // engine 0/1 (waves 0-3 / 4-7)
        const int t2 = tid & 255;
        unsigned char* sm = smem + eng * 34816;
        const int wv = t2 >> 6, lane = t2 & 63;
        const int li = wv * 2;
        const int srow = lane >> 2;          // 0..15
        const int scol = (lane & 3) * 8;     // 0,8,16,24
        const int wm = (wv & 1) * 64, wn = (wv >> 1) * 64;
        const int lr = lane & 15, lq = lane >> 4;

        for (int rd = 0; rd < 3; ++rd) {
            const int t = bid * 6 + eng * 3 + rd;   // 0..1535, bijective
            const int m0 = (t / 12) * 128;
            const int nb = t % 12;
            const int n0g = nb * 128;
            const int pz = nb >> 2;          // 0=q 1=k 2=v
            const int n0 = n0g & 511;
            const float* bias = (pz == 0) ? bq : ((pz == 1) ? bk : bv);
            floatx4 acc[4][4] = {};
            _Float16* R = (_Float16*)sm;     // repack overlay, post-loop only

            auto stage = [&](int tt, int buf) {
                _Float16* Ab = (_Float16*)(sm + buf * 16384);
                _Float16* Bt = (_Float16*)(sm + buf * 16384 + 8192);
                const int kk = tt * 32;
#pragma unroll
                for (int inst = 0; inst < 2; ++inst) {
                    int rr = (li + inst) * 16 + srow;
                    gl_lds16(xb + (size_t)(m0 + rr) * Dd + kk + scol, Ab + (li + inst) * 512 + lane * 8);
                    gl_lds16(wt + (size_t)(n0g + rr) * Dd + kk + scol, Bt + (li + inst) * 512 + lane * 8);
                }
            };

            stage(0, 0);
            for (int it = 0; it < 16; ++it) {
                const int cur = it & 1;
                __syncthreads();             // buf[cur] ready (both engines aligned)
                if (it < 15) stage(it + 1, cur ^ 1);
                const _Float16* Ab = (const _Float16*)(sm + cur * 16384);
                const _Float16* Bt = (const _Float16*)(sm + cur * 16384 + 8192);
                half8 af[4], bf[4];
#pragma unroll
                for (int mi = 0; mi < 4; ++mi)
                    af[mi] = *(const half8*)&Ab[(wm + mi * 16 + lr) * 32 + lq * 8];
#pragma unroll
                for (int ni = 0; ni < 4; ++ni)
                    bf[ni] = *(const half8*)&Bt[(wn + ni * 16 + lr) * 32 + lq * 8];
#pragma unroll
                for (int mi = 0; mi < 4; ++mi)
#pragma unroll
                    for (int ni = 0; ni < 4; ++ni)
                        acc[mi][ni] = __builtin_amdgcn_mfma_f32_16x16x32_f16(af[mi], bf[ni], acc[mi][ni], 0, 0, 0);
            }
            __syncthreads();                 // staging dead; R may overwrite

            // epilogue: bias + repack through LDS, coalesced half8 stores
#pragma unroll
            for (int ni = 0; ni < 4; ++ni) {
                const int gn_l = wn + ni * 16 + lr;
                const float bb = bias[n0 + gn_l];
#pragma unroll
                for (int mi = 0; mi < 4; ++mi) {
#pragma unroll
                    for (int rr = 0; rr < 4; ++rr) {
                        const int gm_l = wm + mi * 16 + lq * 4 + rr;
                        const float v = acc[mi][ni][rr] + bb;
                        if (pz == 2) R[gn_l * 136 + gm_l] = (_Float16)v;   // v: transposed
                        else         R[gm_l * 136 + gn_l] = (_Float16)v;   // q,k: row-major
                    }
                }
            }
            __syncthreads();
            const int row = t2 >> 1, hf = t2 & 1;
            _Float16* dst;
            if (pz == 0)      dst = qo + (size_t)(m0 + row) * Dd + n0 + hf * 64;
            else if (pz == 1) dst = ko + (size_t)(m0 + row) * Dd + n0 + hf * 64;
            else              dst = vto + ((size_t)(m0 >> 11) * Dd + n0 + row) * Ss + (m0 & 2047) + hf * 64;
#pragma unroll
            for (int j = 0; j < 8; ++j)
                *(half8*)(dst + j * 8) = *(const half8*)&R[row * 136 + hf * 64 + j * 8];
            __syncthreads();                 // R reads done before next round's stage
        }
    }

    __threadfence();                         // device-scope release of q/k/vt
    cg::this_grid().sync();                  // all 256 blocks co-resident (1/CU)

    // ================= phase B: flash attention (frozen r0 body) =================
    {
        _Float16* Klds = (_Float16*)smem;                       // 66,560 B
        _Float16* Vlds = (_Float16*)(smem + 66560);             // 65,536 B
        _Float16* P    = (_Float16*)(smem + 132096);            // 10,240 B
        float*    lsum = (float*)(smem + 142336);               // 512 B  (lsum[c*64+i])
        const int b = bid >> 5;
        const int qrow0 = (bid & 31) * 64;
        const int wv = tid >> 6, lane = tid & 63;
        const int lr = lane & 15, lq = lane >> 4;
        const int r = wv >> 1, c = wv & 1;   // score roles
        const int d = wv;                    // PV role
        const _Float16* Qb = qo + (size_t)b * Ss * Dd;
        const _Float16* Kb = ko + (size_t)b * Ss * Dd;
        const _Float16* Vb = vto + (size_t)b * Dd * Ss;

        half8 qf[16];
#pragma unroll
        for (int s = 0; s < 16; ++s)
            qf[s] = *(const half8*)&Qb[(size_t)(qrow0 + r * 16 + lr) * Dd + s * 32 + lq * 8];

        const _Float16* kbase = Kb + (size_t)(wv * 4) * Dd + lane * 8;
        const int kl = (lane & 3) ^ ((lane >> 2) & 3) ^ ((lane >> 4) & 3);
        const _Float16* vbase = Vb + (size_t)(wv * 64 + (lane >> 2)) * Ss + kl * 8;
        const int vsw = lq ^ (lr & 3) ^ ((lr >> 2) & 3);

        floatx4 o[4][4] = {};
        float lp[4] = {0.f, 0.f, 0.f, 0.f};
        const float c1 = 0.044194173824159216f * 1.4426950408889634f;
        const float c2 = 12.0f * 1.4426950408889634f;

#pragma unroll
        for (int j = 0; j < 4; ++j)
            gl_lds16(kbase + (size_t)j * Dd, Klds + (wv * 4 + j) * KSTR + lane * 8);

        for (int kt = 0; kt <= 64; ++kt) {
            const int cur = kt & 1, prv = cur ^ 1;
            __syncthreads();

            if (kt < 64) {
                if (kt < 63) {
                    const _Float16* ks = kbase + (size_t)(kt + 1) * 32 * Dd;
                    _Float16* kd = Klds + prv * (32 * KSTR) + wv * 4 * KSTR + lane * 8;
#pragma unroll
                    for (int j = 0; j < 4; ++j)
                        gl_lds16(ks + (size_t)j * Dd, kd + j * KSTR);
                }
                {
                    const _Float16* vs = vbase + kt * 32;
                    _Float16* vd = Vlds + cur * (512 * 32) + wv * 2048 + lane * 8;
#pragma unroll
                    for (int j = 0; j < 4; ++j)
                        gl_lds16(vs + (size_t)j * 16 * Ss, vd + j * 512);
                }
                floatx4 s[2] = {};
                const _Float16* Kc = Klds + cur * (32 * KSTR) + (c * 16 + lr) * KSTR + lq * 8;
#pragma unroll
                for (int kk = 0; kk < 16; ++kk) {
                    half8 kf = *(const half8*)(Kc + kk * 32);
                    s[kk & 1] = __builtin_amdgcn_mfma_f32_16x16x32_f16(qf[kk], kf, s[kk & 1], 0, 0, 0);
                }
                _Float16* Pc = P + cur * (64 * PSTR);
#pragma unroll
                for (int i = 0; i < 4; ++i) {
                    float p = __builtin_amdgcn_exp2f((s[0][i] + s[1][i]) * c1 - c2);
                    lp[i] += p;
                    Pc[(r * 16 + lq * 4 + i) * PSTR + c * 16 + lr] = (_Float16)p;
                }
            }
            if (kt > 0) {
                const _Float16* Pp = P + prv * (64 * PSTR);
                const _Float16* Vp = Vlds + prv * (512 * 32);
                half8 af[4];
#pragma unroll
                for (int m = 0; m < 4; ++m)
                    af[m] = *(const half8*)&Pp[(m * 16 + lr) * PSTR + lq * 8];
#pragma unroll
                for (int nt = 0; nt < 4; ++nt) {
                    half8 vf = *(const half8*)&Vp[(d * 64 + nt * 16 + lr) * 32 + vsw * 8];
#pragma unroll
                    for (int m = 0; m < 4; ++m)
                        o[m][nt] = __builtin_amdgcn_mfma_f32_16x16x32_f16(af[m], vf, o[m][nt], 0, 0, 0);
                }
            }
        }

#pragma unroll
        for (int i = 0; i < 4; ++i) {
#pragma unroll
            for (int m = 1; m < 16; m <<= 1)
                lp[i] += __shfl_xor(lp[i], m);
        }
        if (lr == 0) {
#pragma unroll
            for (int i = 0; i < 4; ++i)
                lsum[c * 64 + r * 16 + lq * 4 + i] = lp[i];
        }
        __syncthreads();

        float* Ob = out + ((size_t)b * Ss + qrow0) * Dd;
#pragma unroll
        for (int m = 0; m < 4; ++m) {
#pragma unroll
            for (int i = 0; i < 4; ++i) {
                const int rl = m * 16 + lq * 4 + i;
                const float inv = 1.0f / (lsum[rl] + lsum[64 + rl]);
#pragma unroll
                for (int nt = 0; nt < 4; ++nt)
                    Ob[(size_t)rl * Dd + d * 64 + nt * 16 + lr] = o[m][nt][i] * inv;
            }
        }
    }
}

// ---------------- launch ----------------
extern "C" void kernel_launch(void* const* d_in, const int* in_sizes, int n_in,
                              void* d_out, int out_size, void* d_ws, size_t ws_size,
                              hipStream_t stream) {
    const float* x  = (const float*)d_in[0];
    const float* Wq = (const float*)d_in[1];
    const float* bq = (const float*)d_in[2];
    const float* Wk = (const float*)d_in[3];
    const float* bk = (const float*)d_in[4];
    const float* Wv = (const float*)d_in[5];
    const float* bv = (const float*)d_in[6];

    const size_t NE = (size_t)Bb * Ss * Dd;  // 8.39M elements
    _Float16* xb  = (_Float16*)d_ws;
    _Float16* qw  = xb + NE;
    _Float16* kw  = qw + NE;
    _Float16* vtw = kw + NE;
    _Float16* wt  = vtw + NE;  // 3 * 512*512 = [1536][512] concat B^T
    float* outp = (float*)d_out;

    prep_kernel<<<dim3(4096 + 768), 256, 0, stream>>>(x, xb, Wq, Wk, Wv, wt);

    void* kargs[] = {(void*)&xb, (void*)&wt, (void*)&bq, (void*)&bk, (void*)&bv,
                     (void*)&qw, (void*)&kw, (void*)&vtw, (void*)&outp};
    hipLaunchCooperativeKernel((const void*)fused_kernel, dim3(256), dim3(512),
                               kargs, 0, stream);
}